// Round 4
// baseline (339.010 us; speedup 1.0000x reference)
//
#include <hip/hip_runtime.h>
#include <hip/hip_bf16.h>
#include <stdint.h>

#define D_MODEL 1024
#define NHEAD   16
#define HDIM    64
#define SEQ     2048
#define BH      64   // 4 batches * 16 heads

typedef short bf16x8 __attribute__((ext_vector_type(8)));
typedef float f32x4  __attribute__((ext_vector_type(4)));

static __device__ __forceinline__ float bf2f(ushort u) {
    union { uint32_t i; float f; } v; v.i = ((uint32_t)u) << 16; return v.f;
}
static __device__ __forceinline__ ushort f2bf(float f) {
    __hip_bfloat16 h = __float2bfloat16(f);
    union { __hip_bfloat16 h; ushort u; } v; v.h = h; return v.u;
}
static __device__ __forceinline__ uint32_t pk2(float a, float b) {
    return (uint32_t)f2bf(a) | ((uint32_t)f2bf(b) << 16);
}
// Async global->LDS DMA, 16B per lane; lds dest must be wave-uniform.
static __device__ __forceinline__ void gl_lds16(const ushort* g, ushort* l) {
    __builtin_amdgcn_global_load_lds(
        (const __attribute__((address_space(1))) uint32_t*)g,
        (__attribute__((address_space(3))) uint32_t*)l, 16, 0, 0);
}

// ---------------------------------------------------------------------------
// fp32 -> bf16 pre-convert (RNE), 8 elems/thread. Three source buffers fused
// into one launch (block ranges: X | Wqkv | Wout).
// ---------------------------------------------------------------------------
__global__ __launch_bounds__(256)
void cvt_k(const float* __restrict__ s0, ushort* __restrict__ d0,
           const float* __restrict__ s1, ushort* __restrict__ d1,
           const float* __restrict__ s2, ushort* __restrict__ d2)
{
    int blk = blockIdx.x;
    const float* src; ushort* dst;
    if (blk < 4096)      { src = s0; dst = d0; }
    else if (blk < 5632) { src = s1; dst = d1; blk -= 4096; }
    else                 { src = s2; dst = d2; blk -= 5632; }
    const size_t i = ((size_t)blk * 256 + threadIdx.x) * 8;
    float4 a = *(const float4*)&src[i];
    float4 b = *(const float4*)&src[i + 4];
    uint4 o;
    o.x = pk2(a.x, a.y);
    o.y = pk2(a.z, a.w);
    o.z = pk2(b.x, b.y);
    o.w = pk2(b.z, b.w);
    *(uint4*)&dst[i] = o;
}

// ---------------------------------------------------------------------------
// GEMM1: qkv = Xb[8192,1024](bf16) * Wb[3072,1024](bf16)^T.
// Staging via global_load_lds DMA, XOR-swizzled unpadded 64-stride rows.
// XCD-swizzled block mapping (m-panel-grouped). Scatter epilogue.
// ---------------------------------------------------------------------------
__global__ __launch_bounds__(256)
void gemm_qkv(const ushort* __restrict__ Xb, const ushort* __restrict__ Wb,
              ushort* __restrict__ qb, ushort* __restrict__ kb,
              ushort* __restrict__ vt)
{
    __shared__ ushort As[128 * 64];
    __shared__ ushort Bs[128 * 64];
    const int K = 1024;
    const int lid = blockIdx.x + blockIdx.y * 24;
    const int nl  = (lid & 7) * 192 + (lid >> 3);
    const int n0 = (nl % 24) * 128;
    const int m0 = (nl / 24) * 128;
    const int t = threadIdx.x;
    const int lane = t & 63, wv = t >> 6;
    const int wm = (wv >> 1) * 64, wn = (wv & 1) * 64;
    const int l15 = lane & 15, quad = lane >> 4;

    const int rsub = lane >> 3;
    const int cg   = (lane & 7) ^ rsub;            // swizzled global chunk
    const int x7  = l15 & 7;
    const int rdk[2] = { ((quad ^ x7) * 8), (((quad + 4) ^ x7) * 8) };

    f32x4 acc[4][4];
#pragma unroll
    for (int i = 0; i < 4; i++)
#pragma unroll
        for (int j = 0; j < 4; j++) acc[i][j] = (f32x4){0.f, 0.f, 0.f, 0.f};

    for (int k0 = 0; k0 < K; k0 += 64) {
        __syncthreads();
#pragma unroll
        for (int i = 0; i < 4; i++) {
            const int rbase = i * 32 + wv * 8;
            gl_lds16(&Xb[(size_t)(m0 + rbase + rsub) * K + k0 + cg * 8], &As[rbase * 64]);
            gl_lds16(&Wb[(size_t)(n0 + rbase + rsub) * K + k0 + cg * 8], &Bs[rbase * 64]);
        }
        __syncthreads();
#pragma unroll
        for (int ks = 0; ks < 2; ks++) {
            bf16x8 af[4], bfr[4];
#pragma unroll
            for (int mi = 0; mi < 4; mi++)
                af[mi] = *(const bf16x8*)&As[(wm + mi * 16 + l15) * 64 + rdk[ks]];
#pragma unroll
            for (int ni = 0; ni < 4; ni++)
                bfr[ni] = *(const bf16x8*)&Bs[(wn + ni * 16 + l15) * 64 + rdk[ks]];
#pragma unroll
            for (int ni = 0; ni < 4; ni++)
#pragma unroll
                for (int mi = 0; mi < 4; mi++)
                    acc[mi][ni] = __builtin_amdgcn_mfma_f32_16x16x32_bf16(
                        af[mi], bfr[ni], acc[mi][ni], 0, 0, 0);
        }
    }

#pragma unroll
    for (int ni = 0; ni < 4; ni++) {
        const int e = n0 + wn + ni * 16 + l15;
        const int which = e >> 10;
        const int h = (e >> 6) & 15;
        const int d = e & 63;
#pragma unroll
        for (int mi = 0; mi < 4; mi++) {
            const int gm0 = m0 + wm + mi * 16 + quad * 4;
            const int b = gm0 >> 11;
            const int s0 = gm0 & 2047;
            const int bh = b * NHEAD + h;
            if (which == 2) {
                ushort4 pk;
                pk.x = f2bf(acc[mi][ni][0]); pk.y = f2bf(acc[mi][ni][1]);
                pk.z = f2bf(acc[mi][ni][2]); pk.w = f2bf(acc[mi][ni][3]);
                *(ushort4*)&vt[((size_t)bh * HDIM + d) * SEQ + s0] = pk;
            } else {
                ushort* dst = (which == 0) ? qb : kb;
#pragma unroll
                for (int r = 0; r < 4; r++)
                    dst[((size_t)bh * SEQ + s0 + r) * HDIM + d] = f2bf(acc[mi][ni][r]);
            }
        }
    }
}

// ---------------------------------------------------------------------------
// GEMM2: out(f32) = A[8192,1024](bf16) * Wb[1024,1024](bf16)^T — DMA staging.
// XCD-swizzled block mapping (m-panel-grouped).
// ---------------------------------------------------------------------------
__global__ __launch_bounds__(256)
void gemm_out(const ushort* __restrict__ A, const ushort* __restrict__ Wb,
              float* __restrict__ out)
{
    __shared__ ushort As[128 * 64];
    __shared__ ushort Bs[128 * 64];
    const int K = 1024;
    const int lid = blockIdx.x + blockIdx.y * 8;
    const int nl  = (lid & 7) * 64 + (lid >> 3);
    const int n0 = (nl & 7) * 128;
    const int m0 = (nl >> 3) * 128;
    const int t = threadIdx.x;
    const int lane = t & 63, wv = t >> 6;
    const int wm = (wv >> 1) * 64, wn = (wv & 1) * 64;
    const int l15 = lane & 15, quad = lane >> 4;

    const int rsub = lane >> 3;
    const int cg   = (lane & 7) ^ rsub;
    const int x7  = l15 & 7;
    const int rdk[2] = { ((quad ^ x7) * 8), (((quad + 4) ^ x7) * 8) };

    f32x4 acc[4][4];
#pragma unroll
    for (int i = 0; i < 4; i++)
#pragma unroll
        for (int j = 0; j < 4; j++) acc[i][j] = (f32x4){0.f, 0.f, 0.f, 0.f};

    for (int k0 = 0; k0 < K; k0 += 64) {
        __syncthreads();
#pragma unroll
        for (int i = 0; i < 4; i++) {
            const int rbase = i * 32 + wv * 8;
            gl_lds16(&A[(size_t)(m0 + rbase + rsub) * K + k0 + cg * 8],  &As[rbase * 64]);
            gl_lds16(&Wb[(size_t)(n0 + rbase + rsub) * K + k0 + cg * 8], &Bs[rbase * 64]);
        }
        __syncthreads();
#pragma unroll
        for (int ks = 0; ks < 2; ks++) {
            bf16x8 af[4], bfr[4];
#pragma unroll
            for (int mi = 0; mi < 4; mi++)
                af[mi] = *(const bf16x8*)&As[(wm + mi * 16 + l15) * 64 + rdk[ks]];
#pragma unroll
            for (int ni = 0; ni < 4; ni++)
                bfr[ni] = *(const bf16x8*)&Bs[(wn + ni * 16 + l15) * 64 + rdk[ks]];
#pragma unroll
            for (int ni = 0; ni < 4; ni++)
#pragma unroll
                for (int mi = 0; mi < 4; mi++)
                    acc[mi][ni] = __builtin_amdgcn_mfma_f32_16x16x32_bf16(
                        af[mi], bfr[ni], acc[mi][ni], 0, 0, 0);
        }
    }

#pragma unroll
    for (int ni = 0; ni < 4; ni++) {
        const int n = n0 + wn + ni * 16 + l15;
#pragma unroll
        for (int mi = 0; mi < 4; mi++) {
            const int gm0 = m0 + wm + mi * 16 + quad * 4;
#pragma unroll
            for (int r = 0; r < 4; r++)
                out[(size_t)(gm0 + r) * 1024 + n] = acc[mi][ni][r];
        }
    }
}

// ---------------------------------------------------------------------------
// RoPE in-place on bf16 q and k, layout [bh][s][64].
// 8 pairs/thread (32B vector loads), q+k in the SAME thread sharing cos/sin,
// fast-math __expf/__sincosf. q pre-scaled by 1/sqrt(HDIM)=0.125.
// ---------------------------------------------------------------------------
__global__ __launch_bounds__(256)
void rope_k(ushort* __restrict__ qb, ushort* __restrict__ kb)
{
    const int tid = blockIdx.x * 256 + threadIdx.x;   // BH*SEQ*4 total
    const int g  = tid & 3;
    const int s  = (tid >> 2) & 2047;
    const int bh = tid >> 13;
    const size_t off = ((size_t)bh * SEQ + s) * HDIM + g * 16;

    uint32_t qw[8], kw[8];
    *(uint4*)&qw[0] = *(const uint4*)&qb[off];
    *(uint4*)&qw[4] = *(const uint4*)&qb[off + 8];
    *(uint4*)&kw[0] = *(const uint4*)&kb[off];
    *(uint4*)&kw[4] = *(const uint4*)&kb[off + 8];

    const float sf = (float)s;
#pragma unroll
    for (int j = 0; j < 8; j++) {
        const int i = g * 8 + j;
        const float freq = __expf(-(float)i * (9.2103403719761836f / 32.0f));
        const float ang = sf * freq;
        float sn, cs;
        __sincosf(ang, &sn, &cs);
        const float q1 = bf2f((ushort)(qw[j] & 0xffff));
        const float q2 = bf2f((ushort)(qw[j] >> 16));
        const float k1 = bf2f((ushort)(kw[j] & 0xffff));
        const float k2 = bf2f((ushort)(kw[j] >> 16));
        qw[j] = pk2((q1 * cs - q2 * sn) * 0.125f, (q2 * cs + q1 * sn) * 0.125f);
        kw[j] = pk2(k1 * cs - k2 * sn, k2 * cs + k1 * sn);
    }

    *(uint4*)&qb[off]     = *(uint4*)&qw[0];
    *(uint4*)&qb[off + 8] = *(uint4*)&qw[4];
    *(uint4*)&kb[off]     = *(uint4*)&kw[0];
    *(uint4*)&kb[off + 8] = *(uint4*)&kw[4];
}

// ---------------------------------------------------------------------------
// Flash attention, causal — S^T formulation.
// r9:  causal load-balance (block x does q-tiles {x, 31-x}), dbuf K staging.
// r10: XCD-aware bijective block swizzle; T13 defer-max.
// r11: V tile global->REGISTER (LDS unit ~60-70% busy was the theory; V was
//      8 redundant ds_read_b128 + 2 DMA writes per wave-iter). V is L2-resident
//      (24MB working set post-swizzle); loads issued right after the barrier,
//      consumed in PV ~400cyc later. LDS now K-only (16KB/block).
// ---------------------------------------------------------------------------
__global__ __launch_bounds__(256, 4)
void attn_k(const ushort* __restrict__ qb, const ushort* __restrict__ kb,
            const ushort* __restrict__ vt, ushort* __restrict__ ao)
{
    __shared__ ushort Ks[2][64 * 64];

    // XCD-aware remap: 1024 blocks -> XCD (lid&7) gets contiguous chunk of 128.
    const int lid = blockIdx.x + blockIdx.y * 16;
    const int nl  = ((lid & 7) << 7) | (lid >> 3);
    const int bh    = nl >> 4;        // 0..63
    const int qpair = nl & 15;        // 0..15
    const int t = threadIdx.x;
    const int lane = t & 63, wv = t >> 6;
    const int l15 = lane & 15, quad = lane >> 4;
    const int b = bh >> 4, h = bh & 15;

    const ushort* kB = kb + (size_t)bh * SEQ * HDIM;
    const ushort* vB = vt + (size_t)bh * HDIM * SEQ;

    const int rowA = wv * 16 + (lane >> 3);
    const int cg   = (lane & 7) ^ ((lane >> 3) & 7);
    const int koffA = rowA * HDIM + cg * 8;

    const int x7 = l15 & 7;
    const int rd0 = l15 * 64 + ((quad ^ x7) * 8);
    const int rd1 = l15 * 64 + (((quad + 4) ^ x7) * 8);

    const int qlo = (quad & 1) * 2;
    const bool hi = (quad >= 2);

#define STAGE(bufi, kt_) do {                                          \
        const int k0_ = (kt_) * 64;                                    \
        ushort* ldsK_ = &Ks[(bufi)][wv * 16 * 64];                     \
        gl_lds16(kB + (size_t)k0_ * HDIM + koffA,            ldsK_);          \
        gl_lds16(kB + (size_t)k0_ * HDIM + koffA + 8 * HDIM, ldsK_ + 8 * 64); \
    } while (0)

#pragma unroll 1
    for (int p = 0; p < 2; p++) {
        const int qt = p ? (31 - qpair) : qpair;
        const int q0 = qt * 64;
        const int qg = q0 + wv * 16 + l15;

        const ushort* qaL = qb + ((size_t)bh * SEQ + qg) * HDIM + quad * 8;
        bf16x8 qa[2];
        qa[0] = *(const bf16x8*)(qaL);
        qa[1] = *(const bf16x8*)(qaL + 32);

        f32x4 accO[4];
#pragma unroll
        for (int i = 0; i < 4; i++) accO[i] = (f32x4){0.f, 0.f, 0.f, 0.f};
        float m = -30000.f, l = 0.f;

        // Pass boundary: all waves done reading prior pass's LDS before the
        // prologue DMA overwrites buf 0.
        __syncthreads();
        STAGE(0, 0);

#pragma unroll 1
        for (int kt = 0; kt <= qt; kt++) {
            const int buf = kt & 1;
            const int k0 = kt * 64;
            const ushort* KsB = Ks[buf];
            __syncthreads();               // drains DMA for buf (vmcnt at barrier)
            if (kt < qt) STAGE(buf ^ 1, kt + 1);   // overlap next tile with compute

            // V fragments for THIS tile, global->reg (L2-resident). Issued
            // early; first use is in PV after QK+softmax => latency hidden.
            // vr[mi][ks2] = V^T[d = mi*16+l15][k = k0 + ks2*32 + quad*8 ..+7]
            bf16x8 vr[4][2];
#pragma unroll
            for (int mi = 0; mi < 4; mi++)
#pragma unroll
                for (int ks2 = 0; ks2 < 2; ks2++)
                    vr[mi][ks2] = *(const bf16x8*)
                        &vB[(size_t)(mi * 16 + l15) * SEQ + k0 + ks2 * 32 + quad * 8];

            f32x4 st[4];
#pragma unroll
            for (int mi = 0; mi < 4; mi++) st[mi] = (f32x4){0.f, 0.f, 0.f, 0.f};
            __builtin_amdgcn_s_setprio(1);
#pragma unroll
            for (int mi = 0; mi < 4; mi++) {
                bf16x8 ka0 = *(const bf16x8*)&KsB[mi * 1024 + rd0];
                st[mi] = __builtin_amdgcn_mfma_f32_16x16x32_bf16(ka0, qa[0], st[mi], 0, 0, 0);
            }
#pragma unroll
            for (int mi = 0; mi < 4; mi++) {
                bf16x8 ka1 = *(const bf16x8*)&KsB[mi * 1024 + rd1];
                st[mi] = __builtin_amdgcn_mfma_f32_16x16x32_bf16(ka1, qa[1], st[mi], 0, 0, 0);
            }
            __builtin_amdgcn_s_setprio(0);

            if (kt == qt) {
#pragma unroll
                for (int mi = 0; mi < 4; mi++)
#pragma unroll
                    for (int r = 0; r < 4; r++) {
                        int kg = kt * 64 + mi * 16 + quad * 4 + r;
                        if (kg > qg) st[mi][r] = -30000.f;
                    }
            }

            float a0 = fmaxf(fmaxf(st[0][0], st[0][1]), fmaxf(st[0][2], st[0][3]));
            float a1 = fmaxf(fmaxf(st[1][0], st[1][1]), fmaxf(st[1][2], st[1][3]));
            float a2 = fmaxf(fmaxf(st[2][0], st[2][1]), fmaxf(st[2][2], st[2][3]));
            float a3 = fmaxf(fmaxf(st[3][0], st[3][1]), fmaxf(st[3][2], st[3][3]));
            float mx = fmaxf(fmaxf(a0, a1), fmaxf(a2, a3));
            mx = fmaxf(mx, __shfl_xor(mx, 16));
            mx = fmaxf(mx, __shfl_xor(mx, 32));

            // T13 defer-max: only rescale when the running max grew by >8.
            if (!__all(mx - m <= 8.0f)) {
                const float mnew = fmaxf(m, mx);
                const float alpha = __expf(m - mnew);
#pragma unroll
                for (int mi = 0; mi < 4; mi++)
#pragma unroll
                    for (int r = 0; r < 4; r++) accO[mi][r] *= alpha;
                l *= alpha;
                m = mnew;
            }

            float s0 = 0.f, s1 = 0.f, s2 = 0.f, s3 = 0.f;
#pragma unroll
            for (int mi = 0; mi < 4; mi++) {
                float p0 = __expf(st[mi][0] - m);
                float p1 = __expf(st[mi][1] - m);
                float p2 = __expf(st[mi][2] - m);
                float p3 = __expf(st[mi][3] - m);
                st[mi][0] = p0; st[mi][1] = p1; st[mi][2] = p2; st[mi][3] = p3;
                s0 += p0; s1 += p1; s2 += p2; s3 += p3;
            }
            float ssum = (s0 + s1) + (s2 + s3);
            ssum += __shfl_xor(ssum, 16);
            ssum += __shfl_xor(ssum, 32);
            l += ssum;

            uint32_t pr[4][2];
#pragma unroll
            for (int mi = 0; mi < 4; mi++) {
                pr[mi][0] = pk2(st[mi][0], st[mi][1]);
                pr[mi][1] = pk2(st[mi][2], st[mi][3]);
            }

#pragma unroll
            for (int ks2 = 0; ks2 < 2; ks2++) {
                uint32_t pb[4];
#pragma unroll
                for (int w = 0; w < 4; w++) {
                    int srcLane = (qlo + (w >> 1)) * 16 + l15;
                    uint32_t va = __shfl(pr[ks2 * 2 + 0][w & 1], srcLane);
                    uint32_t vb = __shfl(pr[ks2 * 2 + 1][w & 1], srcLane);
                    pb[w] = hi ? vb : va;
                }
                bf16x8 pfrag;
                *(uint4*)&pfrag = *(uint4*)pb;
                __builtin_amdgcn_s_setprio(1);
#pragma unroll
                for (int mi = 0; mi < 4; mi++) {
                    accO[mi] = __builtin_amdgcn_mfma_f32_16x16x32_bf16(
                        vr[mi][ks2], pfrag, accO[mi], 0, 0, 0);
                }
                __builtin_amdgcn_s_setprio(0);
            }
        }

        const float rl = 1.0f / fmaxf(l, 1e-20f);
#pragma unroll
    for (int mi = 0; mi < 4; mi++) {
            uint2 o;
            o.x = pk2(accO[mi][0] * rl, accO[mi][1] * rl);
            o.y = pk2(accO[mi][2] * rl, accO[mi][3] * rl);
            *(uint2*)&ao[((size_t)(b * SEQ + qg)) * D_MODEL + h * HDIM + mi * 16 + quad * 4] = o;
        }
    }
#undef STAGE
}

// ---------------------------------------------------------------------------
extern "C" void kernel_launch(void* const* d_in, const int* in_sizes, int n_in,
                              void* d_out, int out_size, void* d_ws, size_t ws_size,
                              hipStream_t stream)
{
    (void)out_size; (void)ws_size;
    int ix = 0, iwq = 1, iwo = 2;
    for (int i = 0; i < n_in; i++) {
        if (in_sizes[i] == 4 * SEQ * D_MODEL)          ix  = i;  // 8388608
        else if (in_sizes[i] == 3 * D_MODEL * D_MODEL) iwq = i;  // 3145728
        else if (in_sizes[i] == D_MODEL * D_MODEL)     iwo = i;  // 1048576
    }
    const float* X    = (const float*)d_in[ix];
    const float* Wqkv = (const float*)d_in[iwq];
    const float* Wout = (const float*)d_in[iwo];
    float* out = (float*)d_out;

    char* ws = (char*)d_ws;
    const size_t SZ = (size_t)BH * SEQ * HDIM * sizeof(ushort);  // 16.78 MB
    ushort* xb = (ushort*)(ws);            // X in bf16; reused as ao after gemm_qkv
    ushort* qb = (ushort*)(ws + SZ);
    ushort* kb = (ushort*)(ws + 2 * SZ);
    ushort* vt = (ushort*)(ws + 3 * SZ);
    ushort* wqb = (ushort*)(ws + 4 * SZ);                        // 6.29 MB
    ushort* wob = (ushort*)(ws + 4 * SZ + 3 * (size_t)D_MODEL * D_MODEL * 2);
    ushort* ao = xb;                       // alias: xb dead after gemm_qkv

    cvt_k<<<dim3(6144), 256, 0, stream>>>(X, xb, Wqkv, wqb, Wout, wob);
    gemm_qkv<<<dim3(24, 64), 256, 0, stream>>>(xb, wqb, qb, kb, vt);
    rope_k<<<dim3((BH * SEQ * 4) / 256), 256, 0, stream>>>(qb, kb);
    attn_k<<<dim3(16, 64), 256, 0, stream>>>(qb, kb, vt, ao);
    gemm_out<<<dim3(8, 64), 256, 0, stream>>>(ao, wob, out);
}

// Round 5
// 338.896 us; speedup vs baseline: 1.0003x; 1.0003x over previous
//
#include <hip/hip_runtime.h>
#include <hip/hip_bf16.h>
#include <stdint.h>

#define D_MODEL 1024
#define NHEAD   16
#define HDIM    64
#define SEQ     2048
#define BH      64   // 4 batches * 16 heads

typedef short bf16x8 __attribute__((ext_vector_type(8)));
typedef float f32x4  __attribute__((ext_vector_type(4)));

static __device__ __forceinline__ float bf2f(ushort u) {
    union { uint32_t i; float f; } v; v.i = ((uint32_t)u) << 16; return v.f;
}
static __device__ __forceinline__ ushort f2bf(float f) {
    __hip_bfloat16 h = __float2bfloat16(f);
    union { __hip_bfloat16 h; ushort u; } v; v.h = h; return v.u;
}
static __device__ __forceinline__ uint32_t pk2(float a, float b) {
    return (uint32_t)f2bf(a) | ((uint32_t)f2bf(b) << 16);
}
// Async global->LDS DMA, 16B per lane; lds dest must be wave-uniform.
static __device__ __forceinline__ void gl_lds16(const ushort* g, ushort* l) {
    __builtin_amdgcn_global_load_lds(
        (const __attribute__((address_space(1))) uint32_t*)g,
        (__attribute__((address_space(3))) uint32_t*)l, 16, 0, 0);
}

// ---------------------------------------------------------------------------
// fp32 -> bf16 pre-convert (RNE), 8 elems/thread. Three source buffers fused
// into one launch (block ranges: X | Wqkv | Wout).
// ---------------------------------------------------------------------------
__global__ __launch_bounds__(256)
void cvt_k(const float* __restrict__ s0, ushort* __restrict__ d0,
           const float* __restrict__ s1, ushort* __restrict__ d1,
           const float* __restrict__ s2, ushort* __restrict__ d2)
{
    int blk = blockIdx.x;
    const float* src; ushort* dst;
    if (blk < 4096)      { src = s0; dst = d0; }
    else if (blk < 5632) { src = s1; dst = d1; blk -= 4096; }
    else                 { src = s2; dst = d2; blk -= 5632; }
    const size_t i = ((size_t)blk * 256 + threadIdx.x) * 8;
    float4 a = *(const float4*)&src[i];
    float4 b = *(const float4*)&src[i + 4];
    uint4 o;
    o.x = pk2(a.x, a.y);
    o.y = pk2(a.z, a.w);
    o.z = pk2(b.x, b.y);
    o.w = pk2(b.z, b.w);
    *(uint4*)&dst[i] = o;
}

// ---------------------------------------------------------------------------
// GEMM1: qkv = Xb[8192,1024](bf16) * Wb[3072,1024](bf16)^T.
// Staging via global_load_lds DMA, XOR-swizzled unpadded 64-stride rows.
// XCD-swizzled block mapping (m-panel-grouped). Scatter epilogue.
// ---------------------------------------------------------------------------
__global__ __launch_bounds__(256)
void gemm_qkv(const ushort* __restrict__ Xb, const ushort* __restrict__ Wb,
              ushort* __restrict__ qb, ushort* __restrict__ kb,
              ushort* __restrict__ vt)
{
    __shared__ ushort As[128 * 64];
    __shared__ ushort Bs[128 * 64];
    const int K = 1024;
    const int lid = blockIdx.x + blockIdx.y * 24;
    const int nl  = (lid & 7) * 192 + (lid >> 3);
    const int n0 = (nl % 24) * 128;
    const int m0 = (nl / 24) * 128;
    const int t = threadIdx.x;
    const int lane = t & 63, wv = t >> 6;
    const int wm = (wv >> 1) * 64, wn = (wv & 1) * 64;
    const int l15 = lane & 15, quad = lane >> 4;

    const int rsub = lane >> 3;
    const int cg   = (lane & 7) ^ rsub;            // swizzled global chunk
    const int x7  = l15 & 7;
    const int rdk[2] = { ((quad ^ x7) * 8), (((quad + 4) ^ x7) * 8) };

    f32x4 acc[4][4];
#pragma unroll
    for (int i = 0; i < 4; i++)
#pragma unroll
        for (int j = 0; j < 4; j++) acc[i][j] = (f32x4){0.f, 0.f, 0.f, 0.f};

    for (int k0 = 0; k0 < K; k0 += 64) {
        __syncthreads();
#pragma unroll
        for (int i = 0; i < 4; i++) {
            const int rbase = i * 32 + wv * 8;
            gl_lds16(&Xb[(size_t)(m0 + rbase + rsub) * K + k0 + cg * 8], &As[rbase * 64]);
            gl_lds16(&Wb[(size_t)(n0 + rbase + rsub) * K + k0 + cg * 8], &Bs[rbase * 64]);
        }
        __syncthreads();
#pragma unroll
        for (int ks = 0; ks < 2; ks++) {
            bf16x8 af[4], bfr[4];
#pragma unroll
            for (int mi = 0; mi < 4; mi++)
                af[mi] = *(const bf16x8*)&As[(wm + mi * 16 + l15) * 64 + rdk[ks]];
#pragma unroll
            for (int ni = 0; ni < 4; ni++)
                bfr[ni] = *(const bf16x8*)&Bs[(wn + ni * 16 + l15) * 64 + rdk[ks]];
#pragma unroll
            for (int ni = 0; ni < 4; ni++)
#pragma unroll
                for (int mi = 0; mi < 4; mi++)
                    acc[mi][ni] = __builtin_amdgcn_mfma_f32_16x16x32_bf16(
                        af[mi], bfr[ni], acc[mi][ni], 0, 0, 0);
        }
    }

#pragma unroll
    for (int ni = 0; ni < 4; ni++) {
        const int e = n0 + wn + ni * 16 + l15;
        const int which = e >> 10;
        const int h = (e >> 6) & 15;
        const int d = e & 63;
#pragma unroll
        for (int mi = 0; mi < 4; mi++) {
            const int gm0 = m0 + wm + mi * 16 + quad * 4;
            const int b = gm0 >> 11;
            const int s0 = gm0 & 2047;
            const int bh = b * NHEAD + h;
            if (which == 2) {
                ushort4 pk;
                pk.x = f2bf(acc[mi][ni][0]); pk.y = f2bf(acc[mi][ni][1]);
                pk.z = f2bf(acc[mi][ni][2]); pk.w = f2bf(acc[mi][ni][3]);
                *(ushort4*)&vt[((size_t)bh * HDIM + d) * SEQ + s0] = pk;
            } else {
                ushort* dst = (which == 0) ? qb : kb;
#pragma unroll
                for (int r = 0; r < 4; r++)
                    dst[((size_t)bh * SEQ + s0 + r) * HDIM + d] = f2bf(acc[mi][ni][r]);
            }
        }
    }
}

// ---------------------------------------------------------------------------
// GEMM2: out(f32) = A[8192,1024](bf16) * Wb[1024,1024](bf16)^T — DMA staging.
// XCD-swizzled block mapping (m-panel-grouped).
// ---------------------------------------------------------------------------
__global__ __launch_bounds__(256)
void gemm_out(const ushort* __restrict__ A, const ushort* __restrict__ Wb,
              float* __restrict__ out)
{
    __shared__ ushort As[128 * 64];
    __shared__ ushort Bs[128 * 64];
    const int K = 1024;
    const int lid = blockIdx.x + blockIdx.y * 8;
    const int nl  = (lid & 7) * 64 + (lid >> 3);
    const int n0 = (nl & 7) * 128;
    const int m0 = (nl >> 3) * 128;
    const int t = threadIdx.x;
    const int lane = t & 63, wv = t >> 6;
    const int wm = (wv >> 1) * 64, wn = (wv & 1) * 64;
    const int l15 = lane & 15, quad = lane >> 4;

    const int rsub = lane >> 3;
    const int cg   = (lane & 7) ^ rsub;
    const int x7  = l15 & 7;
    const int rdk[2] = { ((quad ^ x7) * 8), (((quad + 4) ^ x7) * 8) };

    f32x4 acc[4][4];
#pragma unroll
    for (int i = 0; i < 4; i++)
#pragma unroll
        for (int j = 0; j < 4; j++) acc[i][j] = (f32x4){0.f, 0.f, 0.f, 0.f};

    for (int k0 = 0; k0 < K; k0 += 64) {
        __syncthreads();
#pragma unroll
        for (int i = 0; i < 4; i++) {
            const int rbase = i * 32 + wv * 8;
            gl_lds16(&A[(size_t)(m0 + rbase + rsub) * K + k0 + cg * 8],  &As[rbase * 64]);
            gl_lds16(&Wb[(size_t)(n0 + rbase + rsub) * K + k0 + cg * 8], &Bs[rbase * 64]);
        }
        __syncthreads();
#pragma unroll
        for (int ks = 0; ks < 2; ks++) {
            bf16x8 af[4], bfr[4];
#pragma unroll
            for (int mi = 0; mi < 4; mi++)
                af[mi] = *(const bf16x8*)&As[(wm + mi * 16 + l15) * 64 + rdk[ks]];
#pragma unroll
            for (int ni = 0; ni < 4; ni++)
                bfr[ni] = *(const bf16x8*)&Bs[(wn + ni * 16 + l15) * 64 + rdk[ks]];
#pragma unroll
            for (int ni = 0; ni < 4; ni++)
#pragma unroll
                for (int mi = 0; mi < 4; mi++)
                    acc[mi][ni] = __builtin_amdgcn_mfma_f32_16x16x32_bf16(
                        af[mi], bfr[ni], acc[mi][ni], 0, 0, 0);
        }
    }

#pragma unroll
    for (int ni = 0; ni < 4; ni++) {
        const int n = n0 + wn + ni * 16 + l15;
#pragma unroll
        for (int mi = 0; mi < 4; mi++) {
            const int gm0 = m0 + wm + mi * 16 + quad * 4;
#pragma unroll
            for (int r = 0; r < 4; r++)
                out[(size_t)(gm0 + r) * 1024 + n] = acc[mi][ni][r];
        }
    }
}

// ---------------------------------------------------------------------------
// RoPE in-place on bf16 q and k, layout [bh][s][64].
// 8 pairs/thread (32B vector loads), q+k in the SAME thread sharing cos/sin,
// fast-math __expf/__sincosf. q pre-scaled by 1/sqrt(HDIM)=0.125.
// ---------------------------------------------------------------------------
__global__ __launch_bounds__(256)
void rope_k(ushort* __restrict__ qb, ushort* __restrict__ kb)
{
    const int tid = blockIdx.x * 256 + threadIdx.x;   // BH*SEQ*4 total
    const int g  = tid & 3;
    const int s  = (tid >> 2) & 2047;
    const int bh = tid >> 13;
    const size_t off = ((size_t)bh * SEQ + s) * HDIM + g * 16;

    uint32_t qw[8], kw[8];
    *(uint4*)&qw[0] = *(const uint4*)&qb[off];
    *(uint4*)&qw[4] = *(const uint4*)&qb[off + 8];
    *(uint4*)&kw[0] = *(const uint4*)&kb[off];
    *(uint4*)&kw[4] = *(const uint4*)&kb[off + 8];

    const float sf = (float)s;
#pragma unroll
    for (int j = 0; j < 8; j++) {
        const int i = g * 8 + j;
        const float freq = __expf(-(float)i * (9.2103403719761836f / 32.0f));
        const float ang = sf * freq;
        float sn, cs;
        __sincosf(ang, &sn, &cs);
        const float q1 = bf2f((ushort)(qw[j] & 0xffff));
        const float q2 = bf2f((ushort)(qw[j] >> 16));
        const float k1 = bf2f((ushort)(kw[j] & 0xffff));
        const float k2 = bf2f((ushort)(kw[j] >> 16));
        qw[j] = pk2((q1 * cs - q2 * sn) * 0.125f, (q2 * cs + q1 * sn) * 0.125f);
        kw[j] = pk2(k1 * cs - k2 * sn, k2 * cs + k1 * sn);
    }

    *(uint4*)&qb[off]     = *(uint4*)&qw[0];
    *(uint4*)&qb[off + 8] = *(uint4*)&qw[4];
    *(uint4*)&kb[off]     = *(uint4*)&kw[0];
    *(uint4*)&kb[off + 8] = *(uint4*)&kw[4];
}

// ---------------------------------------------------------------------------
// Flash attention, causal — S^T formulation.
// r9:  causal load-balance (block x does q-tiles {x, 31-x}), dbuf K staging.
// r10: XCD-aware bijective block swizzle; T13 defer-max.
// r11: V tile global->REGISTER. REGRESSED (154us): vr loads were issued AFTER
//      the STAGE prefetch; vmcnt retires in order, so PV's wait on vr drained
//      the prefetch too => dbuf destroyed.
// r12: FIX: issue vr loads BEFORE STAGE (vr older in vmcnt queue => PV waits
//      at vmcnt(2), prefetch stays in flight). sched_barrier(0) pins the
//      issue order against compiler load-sinking.
// ---------------------------------------------------------------------------
__global__ __launch_bounds__(256, 4)
void attn_k(const ushort* __restrict__ qb, const ushort* __restrict__ kb,
            const ushort* __restrict__ vt, ushort* __restrict__ ao)
{
    __shared__ ushort Ks[2][64 * 64];

    // XCD-aware remap: 1024 blocks -> XCD (lid&7) gets contiguous chunk of 128.
    const int lid = blockIdx.x + blockIdx.y * 16;
    const int nl  = ((lid & 7) << 7) | (lid >> 3);
    const int bh    = nl >> 4;        // 0..63
    const int qpair = nl & 15;        // 0..15
    const int t = threadIdx.x;
    const int lane = t & 63, wv = t >> 6;
    const int l15 = lane & 15, quad = lane >> 4;
    const int b = bh >> 4, h = bh & 15;

    const ushort* kB = kb + (size_t)bh * SEQ * HDIM;
    const ushort* vB = vt + (size_t)bh * HDIM * SEQ;

    const int rowA = wv * 16 + (lane >> 3);
    const int cg   = (lane & 7) ^ ((lane >> 3) & 7);
    const int koffA = rowA * HDIM + cg * 8;

    const int x7 = l15 & 7;
    const int rd0 = l15 * 64 + ((quad ^ x7) * 8);
    const int rd1 = l15 * 64 + (((quad + 4) ^ x7) * 8);

    const int qlo = (quad & 1) * 2;
    const bool hi = (quad >= 2);

#define STAGE(bufi, kt_) do {                                          \
        const int k0_ = (kt_) * 64;                                    \
        ushort* ldsK_ = &Ks[(bufi)][wv * 16 * 64];                     \
        gl_lds16(kB + (size_t)k0_ * HDIM + koffA,            ldsK_);          \
        gl_lds16(kB + (size_t)k0_ * HDIM + koffA + 8 * HDIM, ldsK_ + 8 * 64); \
    } while (0)

#pragma unroll 1
    for (int p = 0; p < 2; p++) {
        const int qt = p ? (31 - qpair) : qpair;
        const int q0 = qt * 64;
        const int qg = q0 + wv * 16 + l15;

        const ushort* qaL = qb + ((size_t)bh * SEQ + qg) * HDIM + quad * 8;
        bf16x8 qa[2];
        qa[0] = *(const bf16x8*)(qaL);
        qa[1] = *(const bf16x8*)(qaL + 32);

        f32x4 accO[4];
#pragma unroll
        for (int i = 0; i < 4; i++) accO[i] = (f32x4){0.f, 0.f, 0.f, 0.f};
        float m = -30000.f, l = 0.f;

        // Pass boundary: all waves done reading prior pass's LDS before the
        // prologue DMA overwrites buf 0.
        __syncthreads();
        STAGE(0, 0);

#pragma unroll 1
        for (int kt = 0; kt <= qt; kt++) {
            const int buf = kt & 1;
            const int k0 = kt * 64;
            const ushort* KsB = Ks[buf];
            __syncthreads();               // drains DMA for buf (vmcnt at barrier)

            // V fragments for THIS tile, global->reg (L2-resident), issued
            // FIRST so they are OLDER than the STAGE prefetch in the vmcnt
            // queue: PV's wait then leaves the prefetch in flight (vmcnt(2)).
            // vr[mi][ks2] = V^T[d = mi*16+l15][k = k0 + ks2*32 + quad*8 ..+7]
            bf16x8 vr[4][2];
#pragma unroll
            for (int mi = 0; mi < 4; mi++)
#pragma unroll
                for (int ks2 = 0; ks2 < 2; ks2++)
                    vr[mi][ks2] = *(const bf16x8*)
                        &vB[(size_t)(mi * 16 + l15) * SEQ + k0 + ks2 * 32 + quad * 8];
            __builtin_amdgcn_sched_barrier(0);     // pin: vr issue before STAGE

            if (kt < qt) STAGE(buf ^ 1, kt + 1);   // overlap next tile with compute

            f32x4 st[4];
#pragma unroll
            for (int mi = 0; mi < 4; mi++) st[mi] = (f32x4){0.f, 0.f, 0.f, 0.f};
            __builtin_amdgcn_s_setprio(1);
#pragma unroll
            for (int mi = 0; mi < 4; mi++) {
                bf16x8 ka0 = *(const bf16x8*)&KsB[mi * 1024 + rd0];
                st[mi] = __builtin_amdgcn_mfma_f32_16x16x32_bf16(ka0, qa[0], st[mi], 0, 0, 0);
            }
#pragma unroll
            for (int mi = 0; mi < 4; mi++) {
                bf16x8 ka1 = *(const bf16x8*)&KsB[mi * 1024 + rd1];
                st[mi] = __builtin_amdgcn_mfma_f32_16x16x32_bf16(ka1, qa[1], st[mi], 0, 0, 0);
            }
            __builtin_amdgcn_s_setprio(0);

            if (kt == qt) {
#pragma unroll
                for (int mi = 0; mi < 4; mi++)
#pragma unroll
                    for (int r = 0; r < 4; r++) {
                        int kg = kt * 64 + mi * 16 + quad * 4 + r;
                        if (kg > qg) st[mi][r] = -30000.f;
                    }
            }

            float a0 = fmaxf(fmaxf(st[0][0], st[0][1]), fmaxf(st[0][2], st[0][3]));
            float a1 = fmaxf(fmaxf(st[1][0], st[1][1]), fmaxf(st[1][2], st[1][3]));
            float a2 = fmaxf(fmaxf(st[2][0], st[2][1]), fmaxf(st[2][2], st[2][3]));
            float a3 = fmaxf(fmaxf(st[3][0], st[3][1]), fmaxf(st[3][2], st[3][3]));
            float mx = fmaxf(fmaxf(a0, a1), fmaxf(a2, a3));
            mx = fmaxf(mx, __shfl_xor(mx, 16));
            mx = fmaxf(mx, __shfl_xor(mx, 32));

            // T13 defer-max: only rescale when the running max grew by >8.
            if (!__all(mx - m <= 8.0f)) {
                const float mnew = fmaxf(m, mx);
                const float alpha = __expf(m - mnew);
#pragma unroll
                for (int mi = 0; mi < 4; mi++)
#pragma unroll
                    for (int r = 0; r < 4; r++) accO[mi][r] *= alpha;
                l *= alpha;
                m = mnew;
            }

            float s0 = 0.f, s1 = 0.f, s2 = 0.f, s3 = 0.f;
#pragma unroll
            for (int mi = 0; mi < 4; mi++) {
                float p0 = __expf(st[mi][0] - m);
                float p1 = __expf(st[mi][1] - m);
                float p2 = __expf(st[mi][2] - m);
                float p3 = __expf(st[mi][3] - m);
                st[mi][0] = p0; st[mi][1] = p1; st[mi][2] = p2; st[mi][3] = p3;
                s0 += p0; s1 += p1; s2 += p2; s3 += p3;
            }
            float ssum = (s0 + s1) + (s2 + s3);
            ssum += __shfl_xor(ssum, 16);
            ssum += __shfl_xor(ssum, 32);
            l += ssum;

            uint32_t pr[4][2];
#pragma unroll
            for (int mi = 0; mi < 4; mi++) {
                pr[mi][0] = pk2(st[mi][0], st[mi][1]);
                pr[mi][1] = pk2(st[mi][2], st[mi][3]);
            }

#pragma unroll
            for (int ks2 = 0; ks2 < 2; ks2++) {
                uint32_t pb[4];
#pragma unroll
                for (int w = 0; w < 4; w++) {
                    int srcLane = (qlo + (w >> 1)) * 16 + l15;
                    uint32_t va = __shfl(pr[ks2 * 2 + 0][w & 1], srcLane);
                    uint32_t vb = __shfl(pr[ks2 * 2 + 1][w & 1], srcLane);
                    pb[w] = hi ? vb : va;
                }
                bf16x8 pfrag;
                *(uint4*)&pfrag = *(uint4*)pb;
                __builtin_amdgcn_s_setprio(1);
#pragma unroll
                for (int mi = 0; mi < 4; mi++) {
                    accO[mi] = __builtin_amdgcn_mfma_f32_16x16x32_bf16(
                        vr[mi][ks2], pfrag, accO[mi], 0, 0, 0);
                }
                __builtin_amdgcn_s_setprio(0);
            }
        }

        const float rl = 1.0f / fmaxf(l, 1e-20f);
#pragma unroll
        for (int mi = 0; mi < 4; mi++) {
            uint2 o;
            o.x = pk2(accO[mi][0] * rl, accO[mi][1] * rl);
            o.y = pk2(accO[mi][2] * rl, accO[mi][3] * rl);
            *(uint2*)&ao[((size_t)(b * SEQ + qg)) * D_MODEL + h * HDIM + mi * 16 + quad * 4] = o;
        }
    }
#undef STAGE
}

// ---------------------------------------------------------------------------
extern "C" void kernel_launch(void* const* d_in, const int* in_sizes, int n_in,
                              void* d_out, int out_size, void* d_ws, size_t ws_size,
                              hipStream_t stream)
{
    (void)out_size; (void)ws_size;
    int ix = 0, iwq = 1, iwo = 2;
    for (int i = 0; i < n_in; i++) {
        if (in_sizes[i] == 4 * SEQ * D_MODEL)          ix  = i;  // 8388608
        else if (in_sizes[i] == 3 * D_MODEL * D_MODEL) iwq = i;  // 3145728
        else if (in_sizes[i] == D_MODEL * D_MODEL)     iwo = i;  // 1048576
    }
    const float* X    = (const float*)d_in[ix];
    const float* Wqkv = (const float*)d_in[iwq];
    const float* Wout = (const float*)d_in[iwo];
    float* out = (float*)d_out;

    char* ws = (char*)d_ws;
    const size_t SZ = (size_t)BH * SEQ * HDIM * sizeof(ushort);  // 16.78 MB
    ushort* xb = (ushort*)(ws);            // X in bf16; reused as ao after gemm_qkv
    ushort* qb = (ushort*)(ws + SZ);
    ushort* kb = (ushort*)(ws + 2 * SZ);
    ushort* vt = (ushort*)(ws + 3 * SZ);
    ushort* wqb = (ushort*)(ws + 4 * SZ);                        // 6.29 MB
    ushort* wob = (ushort*)(ws + 4 * SZ + 3 * (size_t)D_MODEL * D_MODEL * 2);
    ushort* ao = xb;                       // alias: xb dead after gemm_qkv

    cvt_k<<<dim3(6144), 256, 0, stream>>>(X, xb, Wqkv, wqb, Wout, wob);
    gemm_qkv<<<dim3(24, 64), 256, 0, stream>>>(xb, wqb, qb, kb, vt);
    rope_k<<<dim3((BH * SEQ * 4) / 256), 256, 0, stream>>>(qb, kb);
    attn_k<<<dim3(16, 64), 256, 0, stream>>>(qb, kb, vt, ao);
    gemm_out<<<dim3(8, 64), 256, 0, stream>>>(ao, wob, out);
}

// Round 6
// 298.408 us; speedup vs baseline: 1.1361x; 1.1357x over previous
//
#include <hip/hip_runtime.h>
#include <hip/hip_bf16.h>
#include <stdint.h>

#define D_MODEL 1024
#define NHEAD   16
#define HDIM    64
#define SEQ     2048
#define BH      64   // 4 batches * 16 heads

typedef short bf16x8 __attribute__((ext_vector_type(8)));
typedef float f32x4  __attribute__((ext_vector_type(4)));

static __device__ __forceinline__ float bf2f(ushort u) {
    union { uint32_t i; float f; } v; v.i = ((uint32_t)u) << 16; return v.f;
}
static __device__ __forceinline__ ushort f2bf(float f) {
    __hip_bfloat16 h = __float2bfloat16(f);
    union { __hip_bfloat16 h; ushort u; } v; v.h = h; return v.u;
}
static __device__ __forceinline__ uint32_t pk2(float a, float b) {
    return (uint32_t)f2bf(a) | ((uint32_t)f2bf(b) << 16);
}
// Async global->LDS DMA, 16B per lane; lds dest must be wave-uniform.
static __device__ __forceinline__ void gl_lds16(const ushort* g, ushort* l) {
    __builtin_amdgcn_global_load_lds(
        (const __attribute__((address_space(1))) uint32_t*)g,
        (__attribute__((address_space(3))) uint32_t*)l, 16, 0, 0);
}

// ---------------------------------------------------------------------------
// fp32 -> bf16 pre-convert (RNE), 8 elems/thread. Three source buffers fused
// into one launch (block ranges: X | Wqkv | Wout).
// ---------------------------------------------------------------------------
__global__ __launch_bounds__(256)
void cvt_k(const float* __restrict__ s0, ushort* __restrict__ d0,
           const float* __restrict__ s1, ushort* __restrict__ d1,
           const float* __restrict__ s2, ushort* __restrict__ d2)
{
    int blk = blockIdx.x;
    const float* src; ushort* dst;
    if (blk < 4096)      { src = s0; dst = d0; }
    else if (blk < 5632) { src = s1; dst = d1; blk -= 4096; }
    else                 { src = s2; dst = d2; blk -= 5632; }
    const size_t i = ((size_t)blk * 256 + threadIdx.x) * 8;
    float4 a = *(const float4*)&src[i];
    float4 b = *(const float4*)&src[i + 4];
    uint4 o;
    o.x = pk2(a.x, a.y);
    o.y = pk2(a.z, a.w);
    o.z = pk2(b.x, b.y);
    o.w = pk2(b.z, b.w);
    *(uint4*)&dst[i] = o;
}

// ---------------------------------------------------------------------------
// GEMM1: qkv = Xb[8192,1024](bf16) * Wb[3072,1024](bf16)^T.
// Staging via global_load_lds DMA, XOR-swizzled unpadded 64-stride rows.
// XCD-swizzled block mapping (m-panel-grouped). Scatter epilogue.
// ---------------------------------------------------------------------------
__global__ __launch_bounds__(256)
void gemm_qkv(const ushort* __restrict__ Xb, const ushort* __restrict__ Wb,
              ushort* __restrict__ qb, ushort* __restrict__ kb,
              ushort* __restrict__ vt)
{
    __shared__ ushort As[128 * 64];
    __shared__ ushort Bs[128 * 64];
    const int K = 1024;
    const int lid = blockIdx.x + blockIdx.y * 24;
    const int nl  = (lid & 7) * 192 + (lid >> 3);
    const int n0 = (nl % 24) * 128;
    const int m0 = (nl / 24) * 128;
    const int t = threadIdx.x;
    const int lane = t & 63, wv = t >> 6;
    const int wm = (wv >> 1) * 64, wn = (wv & 1) * 64;
    const int l15 = lane & 15, quad = lane >> 4;

    const int rsub = lane >> 3;
    const int cg   = (lane & 7) ^ rsub;            // swizzled global chunk
    const int x7  = l15 & 7;
    const int rdk[2] = { ((quad ^ x7) * 8), (((quad + 4) ^ x7) * 8) };

    f32x4 acc[4][4];
#pragma unroll
    for (int i = 0; i < 4; i++)
#pragma unroll
        for (int j = 0; j < 4; j++) acc[i][j] = (f32x4){0.f, 0.f, 0.f, 0.f};

    for (int k0 = 0; k0 < K; k0 += 64) {
        __syncthreads();
#pragma unroll
        for (int i = 0; i < 4; i++) {
            const int rbase = i * 32 + wv * 8;
            gl_lds16(&Xb[(size_t)(m0 + rbase + rsub) * K + k0 + cg * 8], &As[rbase * 64]);
            gl_lds16(&Wb[(size_t)(n0 + rbase + rsub) * K + k0 + cg * 8], &Bs[rbase * 64]);
        }
        __syncthreads();
#pragma unroll
        for (int ks = 0; ks < 2; ks++) {
            bf16x8 af[4], bfr[4];
#pragma unroll
            for (int mi = 0; mi < 4; mi++)
                af[mi] = *(const bf16x8*)&As[(wm + mi * 16 + l15) * 64 + rdk[ks]];
#pragma unroll
            for (int ni = 0; ni < 4; ni++)
                bfr[ni] = *(const bf16x8*)&Bs[(wn + ni * 16 + l15) * 64 + rdk[ks]];
#pragma unroll
            for (int ni = 0; ni < 4; ni++)
#pragma unroll
                for (int mi = 0; mi < 4; mi++)
                    acc[mi][ni] = __builtin_amdgcn_mfma_f32_16x16x32_bf16(
                        af[mi], bfr[ni], acc[mi][ni], 0, 0, 0);
        }
    }

#pragma unroll
    for (int ni = 0; ni < 4; ni++) {
        const int e = n0 + wn + ni * 16 + l15;
        const int which = e >> 10;
        const int h = (e >> 6) & 15;
        const int d = e & 63;
#pragma unroll
        for (int mi = 0; mi < 4; mi++) {
            const int gm0 = m0 + wm + mi * 16 + quad * 4;
            const int b = gm0 >> 11;
            const int s0 = gm0 & 2047;
            const int bh = b * NHEAD + h;
            if (which == 2) {
                ushort4 pk;
                pk.x = f2bf(acc[mi][ni][0]); pk.y = f2bf(acc[mi][ni][1]);
                pk.z = f2bf(acc[mi][ni][2]); pk.w = f2bf(acc[mi][ni][3]);
                *(ushort4*)&vt[((size_t)bh * HDIM + d) * SEQ + s0] = pk;
            } else {
                ushort* dst = (which == 0) ? qb : kb;
#pragma unroll
                for (int r = 0; r < 4; r++)
                    dst[((size_t)bh * SEQ + s0 + r) * HDIM + d] = f2bf(acc[mi][ni][r]);
            }
        }
    }
}

// ---------------------------------------------------------------------------
// GEMM2: out(f32) = A[8192,1024](bf16) * Wb[1024,1024](bf16)^T — DMA staging.
// XCD-swizzled block mapping (m-panel-grouped).
// ---------------------------------------------------------------------------
__global__ __launch_bounds__(256)
void gemm_out(const ushort* __restrict__ A, const ushort* __restrict__ Wb,
              float* __restrict__ out)
{
    __shared__ ushort As[128 * 64];
    __shared__ ushort Bs[128 * 64];
    const int K = 1024;
    const int lid = blockIdx.x + blockIdx.y * 8;
    const int nl  = (lid & 7) * 64 + (lid >> 3);
    const int n0 = (nl & 7) * 128;
    const int m0 = (nl >> 3) * 128;
    const int t = threadIdx.x;
    const int lane = t & 63, wv = t >> 6;
    const int wm = (wv >> 1) * 64, wn = (wv & 1) * 64;
    const int l15 = lane & 15, quad = lane >> 4;

    const int rsub = lane >> 3;
    const int cg   = (lane & 7) ^ rsub;
    const int x7  = l15 & 7;
    const int rdk[2] = { ((quad ^ x7) * 8), (((quad + 4) ^ x7) * 8) };

    f32x4 acc[4][4];
#pragma unroll
    for (int i = 0; i < 4; i++)
#pragma unroll
        for (int j = 0; j < 4; j++) acc[i][j] = (f32x4){0.f, 0.f, 0.f, 0.f};

    for (int k0 = 0; k0 < K; k0 += 64) {
        __syncthreads();
#pragma unroll
        for (int i = 0; i < 4; i++) {
            const int rbase = i * 32 + wv * 8;
            gl_lds16(&A[(size_t)(m0 + rbase + rsub) * K + k0 + cg * 8],  &As[rbase * 64]);
            gl_lds16(&Wb[(size_t)(n0 + rbase + rsub) * K + k0 + cg * 8], &Bs[rbase * 64]);
        }
        __syncthreads();
#pragma unroll
        for (int ks = 0; ks < 2; ks++) {
            bf16x8 af[4], bfr[4];
#pragma unroll
            for (int mi = 0; mi < 4; mi++)
                af[mi] = *(const bf16x8*)&As[(wm + mi * 16 + l15) * 64 + rdk[ks]];
#pragma unroll
            for (int ni = 0; ni < 4; ni++)
                bfr[ni] = *(const bf16x8*)&Bs[(wn + ni * 16 + l15) * 64 + rdk[ks]];
#pragma unroll
            for (int ni = 0; ni < 4; ni++)
#pragma unroll
                for (int mi = 0; mi < 4; mi++)
                    acc[mi][ni] = __builtin_amdgcn_mfma_f32_16x16x32_bf16(
                        af[mi], bfr[ni], acc[mi][ni], 0, 0, 0);
        }
    }

#pragma unroll
    for (int ni = 0; ni < 4; ni++) {
        const int n = n0 + wn + ni * 16 + l15;
#pragma unroll
        for (int mi = 0; mi < 4; mi++) {
            const int gm0 = m0 + wm + mi * 16 + quad * 4;
#pragma unroll
            for (int r = 0; r < 4; r++)
                out[(size_t)(gm0 + r) * 1024 + n] = acc[mi][ni][r];
        }
    }
}

// ---------------------------------------------------------------------------
// RoPE in-place on bf16 q and k, layout [bh][s][64].
// 8 pairs/thread (32B vector loads), q+k in the SAME thread sharing cos/sin,
// fast-math __expf/__sincosf. q pre-scaled by 1/sqrt(HDIM)=0.125.
// ---------------------------------------------------------------------------
__global__ __launch_bounds__(256)
void rope_k(ushort* __restrict__ qb, ushort* __restrict__ kb)
{
    const int tid = blockIdx.x * 256 + threadIdx.x;   // BH*SEQ*4 total
    const int g  = tid & 3;
    const int s  = (tid >> 2) & 2047;
    const int bh = tid >> 13;
    const size_t off = ((size_t)bh * SEQ + s) * HDIM + g * 16;

    uint32_t qw[8], kw[8];
    *(uint4*)&qw[0] = *(const uint4*)&qb[off];
    *(uint4*)&qw[4] = *(const uint4*)&qb[off + 8];
    *(uint4*)&kw[0] = *(const uint4*)&kb[off];
    *(uint4*)&kw[4] = *(const uint4*)&kb[off + 8];

    const float sf = (float)s;
#pragma unroll
    for (int j = 0; j < 8; j++) {
        const int i = g * 8 + j;
        const float freq = __expf(-(float)i * (9.2103403719761836f / 32.0f));
        const float ang = sf * freq;
        float sn, cs;
        __sincosf(ang, &sn, &cs);
        const float q1 = bf2f((ushort)(qw[j] & 0xffff));
        const float q2 = bf2f((ushort)(qw[j] >> 16));
        const float k1 = bf2f((ushort)(kw[j] & 0xffff));
        const float k2 = bf2f((ushort)(kw[j] >> 16));
        qw[j] = pk2((q1 * cs - q2 * sn) * 0.125f, (q2 * cs + q1 * sn) * 0.125f);
        kw[j] = pk2(k1 * cs - k2 * sn, k2 * cs + k1 * sn);
    }

    *(uint4*)&qb[off]     = *(uint4*)&qw[0];
    *(uint4*)&qb[off + 8] = *(uint4*)&qw[4];
    *(uint4*)&kb[off]     = *(uint4*)&kw[0];
    *(uint4*)&kb[off + 8] = *(uint4*)&kw[4];
}

// ---------------------------------------------------------------------------
// Flash attention, causal — S^T formulation.
// r13: REVERT to the R2 structure (V staged in LDS via DMA — V-in-reg was a
//      2x regression in r11/r12: 16x scattered 64B segments, 4x redundancy).
//      Occupancy attack instead: 2048 UNPAIRED blocks (one 64-row q-tile
//      each, 32KB LDS => 5 resident blocks/CU = 20 waves, rest queued and
//      backfilled by HW), longest-tile-first dispatch order inside each
//      XCD's bh-chunk so the 32-iter blocks start at t=0.
//      Keeps: dbuf K+V staging, XCD swizzle, defer-max, setprio.
// ---------------------------------------------------------------------------
__global__ __launch_bounds__(256, 4)
void attn_k(const ushort* __restrict__ qb, const ushort* __restrict__ kb,
            const ushort* __restrict__ vt, ushort* __restrict__ ao)
{
    __shared__ ushort Ks[2][64 * 64];
    __shared__ ushort Vs[2][64 * 64];   // V^T tile: row = d, col = k_local (swizzled)

    // XCD-aware remap: 2048 blocks -> XCD (lid&7) owns nl chunk of 256
    // (= bh 8i..8i+7). Within a chunk qt DESCENDS so longest blocks launch
    // first (dispatch follows blockIdx order; queued shorts backfill).
    const int lid = blockIdx.x + blockIdx.y * 32;
    const int nl  = ((lid & 7) << 8) | (lid >> 3);
    const int bh  = nl >> 5;              // 0..63
    const int qt  = 31 - (nl & 31);       // longest first
    const int t = threadIdx.x;
    const int lane = t & 63, wv = t >> 6;
    const int l15 = lane & 15, quad = lane >> 4;
    const int b = bh >> 4, h = bh & 15;

    const ushort* kB = kb + (size_t)bh * SEQ * HDIM;
    const ushort* vB = vt + (size_t)bh * HDIM * SEQ;

    const int rowA = wv * 16 + (lane >> 3);
    const int cg   = (lane & 7) ^ ((lane >> 3) & 7);
    const int koffA = rowA * HDIM + cg * 8;
    const int voffA = rowA * SEQ + cg * 8;

    const int x7 = l15 & 7;
    const int rd0 = l15 * 64 + ((quad ^ x7) * 8);
    const int rd1 = l15 * 64 + (((quad + 4) ^ x7) * 8);

    const int qlo = (quad & 1) * 2;
    const bool hi = (quad >= 2);

#define STAGE(bufi, kt_) do {                                          \
        const int k0_ = (kt_) * 64;                                    \
        ushort* ldsK_ = &Ks[(bufi)][wv * 16 * 64];                     \
        ushort* ldsV_ = &Vs[(bufi)][wv * 16 * 64];                     \
        gl_lds16(kB + (size_t)k0_ * HDIM + koffA,            ldsK_);          \
        gl_lds16(kB + (size_t)k0_ * HDIM + koffA + 8 * HDIM, ldsK_ + 8 * 64); \
        gl_lds16(vB + (size_t)k0_ + voffA,                   ldsV_);          \
        gl_lds16(vB + (size_t)k0_ + voffA + 8 * SEQ,         ldsV_ + 8 * 64); \
    } while (0)

    const int q0 = qt * 64;
    const int qg = q0 + wv * 16 + l15;

    const ushort* qaL = qb + ((size_t)bh * SEQ + qg) * HDIM + quad * 8;
    bf16x8 qa[2];
    qa[0] = *(const bf16x8*)(qaL);
    qa[1] = *(const bf16x8*)(qaL + 32);

    f32x4 accO[4];
#pragma unroll
    for (int i = 0; i < 4; i++) accO[i] = (f32x4){0.f, 0.f, 0.f, 0.f};
    float m = -30000.f, l = 0.f;

    STAGE(0, 0);

#pragma unroll 1
    for (int kt = 0; kt <= qt; kt++) {
        const int buf = kt & 1;
        const ushort* KsB = Ks[buf];
        const ushort* VsB = Vs[buf];
        __syncthreads();               // drains DMA for buf (vmcnt at barrier)
        if (kt < qt) STAGE(buf ^ 1, kt + 1);   // overlap next tile with compute

        f32x4 st[4];
#pragma unroll
        for (int mi = 0; mi < 4; mi++) st[mi] = (f32x4){0.f, 0.f, 0.f, 0.f};
        __builtin_amdgcn_s_setprio(1);
#pragma unroll
        for (int mi = 0; mi < 4; mi++) {
            bf16x8 ka0 = *(const bf16x8*)&KsB[mi * 1024 + rd0];
            st[mi] = __builtin_amdgcn_mfma_f32_16x16x32_bf16(ka0, qa[0], st[mi], 0, 0, 0);
        }
#pragma unroll
        for (int mi = 0; mi < 4; mi++) {
            bf16x8 ka1 = *(const bf16x8*)&KsB[mi * 1024 + rd1];
            st[mi] = __builtin_amdgcn_mfma_f32_16x16x32_bf16(ka1, qa[1], st[mi], 0, 0, 0);
        }
        __builtin_amdgcn_s_setprio(0);

        if (kt == qt) {
#pragma unroll
            for (int mi = 0; mi < 4; mi++)
#pragma unroll
                for (int r = 0; r < 4; r++) {
                    int kg = kt * 64 + mi * 16 + quad * 4 + r;
                    if (kg > qg) st[mi][r] = -30000.f;
                }
        }

        float a0 = fmaxf(fmaxf(st[0][0], st[0][1]), fmaxf(st[0][2], st[0][3]));
        float a1 = fmaxf(fmaxf(st[1][0], st[1][1]), fmaxf(st[1][2], st[1][3]));
        float a2 = fmaxf(fmaxf(st[2][0], st[2][1]), fmaxf(st[2][2], st[2][3]));
        float a3 = fmaxf(fmaxf(st[3][0], st[3][1]), fmaxf(st[3][2], st[3][3]));
        float mx = fmaxf(fmaxf(a0, a1), fmaxf(a2, a3));
        mx = fmaxf(mx, __shfl_xor(mx, 16));
        mx = fmaxf(mx, __shfl_xor(mx, 32));

        // T13 defer-max: only rescale when the running max grew by >8.
        if (!__all(mx - m <= 8.0f)) {
            const float mnew = fmaxf(m, mx);
            const float alpha = __expf(m - mnew);
#pragma unroll
            for (int mi = 0; mi < 4; mi++)
#pragma unroll
                for (int r = 0; r < 4; r++) accO[mi][r] *= alpha;
            l *= alpha;
            m = mnew;
        }

        float s0 = 0.f, s1 = 0.f, s2 = 0.f, s3 = 0.f;
#pragma unroll
        for (int mi = 0; mi < 4; mi++) {
            float p0 = __expf(st[mi][0] - m);
            float p1 = __expf(st[mi][1] - m);
            float p2 = __expf(st[mi][2] - m);
            float p3 = __expf(st[mi][3] - m);
            st[mi][0] = p0; st[mi][1] = p1; st[mi][2] = p2; st[mi][3] = p3;
            s0 += p0; s1 += p1; s2 += p2; s3 += p3;
        }
        float ssum = (s0 + s1) + (s2 + s3);
        ssum += __shfl_xor(ssum, 16);
        ssum += __shfl_xor(ssum, 32);
        l += ssum;

        uint32_t pr[4][2];
#pragma unroll
        for (int mi = 0; mi < 4; mi++) {
            pr[mi][0] = pk2(st[mi][0], st[mi][1]);
            pr[mi][1] = pk2(st[mi][2], st[mi][3]);
        }

#pragma unroll
        for (int ks2 = 0; ks2 < 2; ks2++) {
            uint32_t pb[4];
#pragma unroll
            for (int w = 0; w < 4; w++) {
                int srcLane = (qlo + (w >> 1)) * 16 + l15;
                uint32_t va = __shfl(pr[ks2 * 2 + 0][w & 1], srcLane);
                uint32_t vb = __shfl(pr[ks2 * 2 + 1][w & 1], srcLane);
                pb[w] = hi ? vb : va;
            }
            bf16x8 pfrag;
            *(uint4*)&pfrag = *(uint4*)pb;
            const int rdv = ks2 ? rd1 : rd0;
            __builtin_amdgcn_s_setprio(1);
#pragma unroll
            for (int mi = 0; mi < 4; mi++) {
                bf16x8 vfr = *(const bf16x8*)&VsB[mi * 1024 + rdv];
                accO[mi] = __builtin_amdgcn_mfma_f32_16x16x32_bf16(vfr, pfrag, accO[mi], 0, 0, 0);
            }
            __builtin_amdgcn_s_setprio(0);
        }
    }

    const float rl = 1.0f / fmaxf(l, 1e-20f);
#pragma unroll
    for (int mi = 0; mi < 4; mi++) {
        uint2 o;
        o.x = pk2(accO[mi][0] * rl, accO[mi][1] * rl);
        o.y = pk2(accO[mi][2] * rl, accO[mi][3] * rl);
        *(uint2*)&ao[((size_t)(b * SEQ + qg)) * D_MODEL + h * HDIM + mi * 16 + quad * 4] = o;
    }
#undef STAGE
}

// ---------------------------------------------------------------------------
extern "C" void kernel_launch(void* const* d_in, const int* in_sizes, int n_in,
                              void* d_out, int out_size, void* d_ws, size_t ws_size,
                              hipStream_t stream)
{
    (void)out_size; (void)ws_size;
    int ix = 0, iwq = 1, iwo = 2;
    for (int i = 0; i < n_in; i++) {
        if (in_sizes[i] == 4 * SEQ * D_MODEL)          ix  = i;  // 8388608
        else if (in_sizes[i] == 3 * D_MODEL * D_MODEL) iwq = i;  // 3145728
        else if (in_sizes[i] == D_MODEL * D_MODEL)     iwo = i;  // 1048576
    }
    const float* X    = (const float*)d_in[ix];
    const float* Wqkv = (const float*)d_in[iwq];
    const float* Wout = (const float*)d_in[iwo];
    float* out = (float*)d_out;

    char* ws = (char*)d_ws;
    const size_t SZ = (size_t)BH * SEQ * HDIM * sizeof(ushort);  // 16.78 MB
    ushort* xb = (ushort*)(ws);            // X in bf16; reused as ao after gemm_qkv
    ushort* qb = (ushort*)(ws + SZ);
    ushort* kb = (ushort*)(ws + 2 * SZ);
    ushort* vt = (ushort*)(ws + 3 * SZ);
    ushort* wqb = (ushort*)(ws + 4 * SZ);                        // 6.29 MB
    ushort* wob = (ushort*)(ws + 4 * SZ + 3 * (size_t)D_MODEL * D_MODEL * 2);
    ushort* ao = xb;                       // alias: xb dead after gemm_qkv

    cvt_k<<<dim3(6144), 256, 0, stream>>>(X, xb, Wqkv, wqb, Wout, wob);
    gemm_qkv<<<dim3(24, 64), 256, 0, stream>>>(xb, wqb, qb, kb, vt);
    rope_k<<<dim3((BH * SEQ * 4) / 256), 256, 0, stream>>>(qb, kb);
    attn_k<<<dim3(32, 64), 256, 0, stream>>>(qb, kb, vt, ao);
    gemm_out<<<dim3(8, 64), 256, 0, stream>>>(ao, wob, out);
}

// Round 8
// 270.981 us; speedup vs baseline: 1.2510x; 1.1012x over previous
//
#include <hip/hip_runtime.h>
#include <hip/hip_bf16.h>
#include <stdint.h>

#define D_MODEL 1024
#define NHEAD   16
#define HDIM    64
#define SEQ     2048
#define BH      64   // 4 batches * 16 heads

typedef short bf16x8 __attribute__((ext_vector_type(8)));
typedef float f32x4  __attribute__((ext_vector_type(4)));

static __device__ __forceinline__ float bf2f(ushort u) {
    union { uint32_t i; float f; } v; v.i = ((uint32_t)u) << 16; return v.f;
}
static __device__ __forceinline__ ushort f2bf(float f) {
    __hip_bfloat16 h = __float2bfloat16(f);
    union { __hip_bfloat16 h; ushort u; } v; v.h = h; return v.u;
}
static __device__ __forceinline__ uint32_t pk2(float a, float b) {
    return (uint32_t)f2bf(a) | ((uint32_t)f2bf(b) << 16);
}
// Async global->LDS DMA, 16B per lane; lds dest must be wave-uniform.
static __device__ __forceinline__ void gl_lds16(const ushort* g, ushort* l) {
    __builtin_amdgcn_global_load_lds(
        (const __attribute__((address_space(1))) uint32_t*)g,
        (__attribute__((address_space(3))) uint32_t*)l, 16, 0, 0);
}

// ---------------------------------------------------------------------------
// fp32 -> bf16 pre-convert (RNE), 8 elems/thread. Three source buffers fused
// into one launch (block ranges: X | Wqkv | Wout).
// ---------------------------------------------------------------------------
__global__ __launch_bounds__(256)
void cvt_k(const float* __restrict__ s0, ushort* __restrict__ d0,
           const float* __restrict__ s1, ushort* __restrict__ d1,
           const float* __restrict__ s2, ushort* __restrict__ d2)
{
    int blk = blockIdx.x;
    const float* src; ushort* dst;
    if (blk < 4096)      { src = s0; dst = d0; }
    else if (blk < 5632) { src = s1; dst = d1; blk -= 4096; }
    else                 { src = s2; dst = d2; blk -= 5632; }
    const size_t i = ((size_t)blk * 256 + threadIdx.x) * 8;
    float4 a = *(const float4*)&src[i];
    float4 b = *(const float4*)&src[i + 4];
    uint4 o;
    o.x = pk2(a.x, a.y);
    o.y = pk2(a.z, a.w);
    o.z = pk2(b.x, b.y);
    o.w = pk2(b.z, b.w);
    *(uint4*)&dst[i] = o;
}

// ---------------------------------------------------------------------------
// GEMM1: qkv = Xb[8192,1024](bf16) * Wb[3072,1024](bf16)^T.
// Staging via global_load_lds DMA, XOR-swizzled unpadded 64-stride rows.
// XCD-swizzled block mapping (m-panel-grouped).
// r14: RoPE FUSED into the epilogue. `which` is block-uniform (128-col tiles
// never straddle the q/k/v 1024-boundaries); the d-pair partner x[d^1] is in
// lane l15^1 => one __shfl_xor per element; 16 sincos/lane once per block.
// Applied to f32 accumulators BEFORE the single bf16 rounding (more accurate
// than the old separate bf16 read-modify-write pass). q pre-scaled 0.125.
// ---------------------------------------------------------------------------
__global__ __launch_bounds__(256)
void gemm_qkv(const ushort* __restrict__ Xb, const ushort* __restrict__ Wb,
              ushort* __restrict__ qb, ushort* __restrict__ kb,
              ushort* __restrict__ vt)
{
    __shared__ ushort As[128 * 64];
    __shared__ ushort Bs[128 * 64];
    const int K = 1024;
    const int lid = blockIdx.x + blockIdx.y * 24;
    const int nl  = (lid & 7) * 192 + (lid >> 3);
    const int n0 = (nl % 24) * 128;
    const int m0 = (nl / 24) * 128;
    const int t = threadIdx.x;
    const int lane = t & 63, wv = t >> 6;
    const int wm = (wv >> 1) * 64, wn = (wv & 1) * 64;
    const int l15 = lane & 15, quad = lane >> 4;

    const int rsub = lane >> 3;
    const int cg   = (lane & 7) ^ rsub;            // swizzled global chunk
    const int x7  = l15 & 7;
    const int rdk[2] = { ((quad ^ x7) * 8), (((quad + 4) ^ x7) * 8) };

    f32x4 acc[4][4];
#pragma unroll
    for (int i = 0; i < 4; i++)
#pragma unroll
        for (int j = 0; j < 4; j++) acc[i][j] = (f32x4){0.f, 0.f, 0.f, 0.f};

    for (int k0 = 0; k0 < K; k0 += 64) {
        __syncthreads();
#pragma unroll
        for (int i = 0; i < 4; i++) {
            const int rbase = i * 32 + wv * 8;
            gl_lds16(&Xb[(size_t)(m0 + rbase + rsub) * K + k0 + cg * 8], &As[rbase * 64]);
            gl_lds16(&Wb[(size_t)(n0 + rbase + rsub) * K + k0 + cg * 8], &Bs[rbase * 64]);
        }
        __syncthreads();
#pragma unroll
        for (int ks = 0; ks < 2; ks++) {
            bf16x8 af[4], bfr[4];
#pragma unroll
            for (int mi = 0; mi < 4; mi++)
                af[mi] = *(const bf16x8*)&As[(wm + mi * 16 + l15) * 64 + rdk[ks]];
#pragma unroll
            for (int ni = 0; ni < 4; ni++)
                bfr[ni] = *(const bf16x8*)&Bs[(wn + ni * 16 + l15) * 64 + rdk[ks]];
#pragma unroll
            for (int ni = 0; ni < 4; ni++)
#pragma unroll
                for (int mi = 0; mi < 4; mi++)
                    acc[mi][ni] = __builtin_amdgcn_mfma_f32_16x16x32_bf16(
                        af[mi], bfr[ni], acc[mi][ni], 0, 0, 0);
        }
    }

#pragma unroll
    for (int ni = 0; ni < 4; ni++) {
        const int e = n0 + wn + ni * 16 + l15;
        const int which = e >> 10;     // block-uniform (tiles don't straddle)
        const int h = (e >> 6) & 15;
        const int d = e & 63;
#pragma unroll
        for (int mi = 0; mi < 4; mi++) {
            const int gm0 = m0 + wm + mi * 16 + quad * 4;
            const int b = gm0 >> 11;
            const int s0 = gm0 & 2047;
            const int bh = b * NHEAD + h;
            if (which == 2) {
                ushort4 pk;
                pk.x = f2bf(acc[mi][ni][0]); pk.y = f2bf(acc[mi][ni][1]);
                pk.z = f2bf(acc[mi][ni][2]); pk.w = f2bf(acc[mi][ni][3]);
                *(ushort4*)&vt[((size_t)bh * HDIM + d) * SEQ + s0] = pk;
            } else {
                ushort* dst = (which == 0) ? qb : kb;
                const float post = (which == 0) ? 0.125f : 1.0f;
                // RoPE: freq = 10000^{-(d>>1)/32}; partner x[d^1] from lane^1.
                const float freq = __expf(-(float)(d >> 1) * (9.2103403719761836f / 32.0f));
                const float sgn = (d & 1) ? 1.0f : -1.0f;
#pragma unroll
                for (int r = 0; r < 4; r++) {
                    const float v = acc[mi][ni][r];
                    const float p = __shfl_xor(v, 1);
                    float sn, cs;
                    __sincosf((float)(s0 + r) * freq, &sn, &cs);
                    dst[((size_t)bh * SEQ + s0 + r) * HDIM + d] =
                        f2bf((v * cs + sgn * p * sn) * post);
                }
            }
        }
    }
}

// ---------------------------------------------------------------------------
// GEMM2: out(f32) = A[8192,1024](bf16) * Wb[1024,1024](bf16)^T — DMA staging.
// XCD-swizzled block mapping (m-panel-grouped).
// ---------------------------------------------------------------------------
__global__ __launch_bounds__(256)
void gemm_out(const ushort* __restrict__ A, const ushort* __restrict__ Wb,
              float* __restrict__ out)
{
    __shared__ ushort As[128 * 64];
    __shared__ ushort Bs[128 * 64];
    const int K = 1024;
    const int lid = blockIdx.x + blockIdx.y * 8;
    const int nl  = (lid & 7) * 64 + (lid >> 3);
    const int n0 = (nl & 7) * 128;
    const int m0 = (nl >> 3) * 128;
    const int t = threadIdx.x;
    const int lane = t & 63, wv = t >> 6;
    const int wm = (wv >> 1) * 64, wn = (wv & 1) * 64;
    const int l15 = lane & 15, quad = lane >> 4;

    const int rsub = lane >> 3;
    const int cg   = (lane & 7) ^ rsub;
    const int x7  = l15 & 7;
    const int rdk[2] = { ((quad ^ x7) * 8), (((quad + 4) ^ x7) * 8) };

    f32x4 acc[4][4];
#pragma unroll
    for (int i = 0; i < 4; i++)
#pragma unroll
        for (int j = 0; j < 4; j++) acc[i][j] = (f32x4){0.f, 0.f, 0.f, 0.f};

    for (int k0 = 0; k0 < K; k0 += 64) {
        __syncthreads();
#pragma unroll
        for (int i = 0; i < 4; i++) {
            const int rbase = i * 32 + wv * 8;
            gl_lds16(&A[(size_t)(m0 + rbase + rsub) * K + k0 + cg * 8],  &As[rbase * 64]);
            gl_lds16(&Wb[(size_t)(n0 + rbase + rsub) * K + k0 + cg * 8], &Bs[rbase * 64]);
        }
        __syncthreads();
#pragma unroll
        for (int ks = 0; ks < 2; ks++) {
            bf16x8 af[4], bfr[4];
#pragma unroll
            for (int mi = 0; mi < 4; mi++)
                af[mi] = *(const bf16x8*)&As[(wm + mi * 16 + l15) * 64 + rdk[ks]];
#pragma unroll
            for (int ni = 0; ni < 4; ni++)
                bfr[ni] = *(const bf16x8*)&Bs[(wn + ni * 16 + l15) * 64 + rdk[ks]];
#pragma unroll
            for (int ni = 0; ni < 4; ni++)
#pragma unroll
                for (int mi = 0; mi < 4; mi++)
                    acc[mi][ni] = __builtin_amdgcn_mfma_f32_16x16x32_bf16(
                        af[mi], bfr[ni], acc[mi][ni], 0, 0, 0);
        }
    }

#pragma unroll
    for (int ni = 0; ni < 4; ni++) {
        const int n = n0 + wn + ni * 16 + l15;
#pragma unroll
        for (int mi = 0; mi < 4; mi++) {
            const int gm0 = m0 + wm + mi * 16 + quad * 4;
#pragma unroll
            for (int r = 0; r < 4; r++)
                out[(size_t)(gm0 + r) * 1024 + n] = acc[mi][ni][r];
        }
    }
}

// ---------------------------------------------------------------------------
// Flash attention, causal — S^T formulation. R2 structure (best measured:
// 93.5us): causal pairing (block x does q-tiles {x, 31-x} => 33 iters each,
// perfectly balanced at the 4-block/CU residency cap), double-buffered K+V
// LDS staging via DMA, XCD-aware bijective swizzle (per-XCD K/V set = 4MB =
// L2), T13 defer-max, setprio around MFMA.
// r11/r12 (V-in-reg) and r13 (oversubscription) both REGRESSED — reverted.
// ---------------------------------------------------------------------------
__global__ __launch_bounds__(256, 4)
void attn_k(const ushort* __restrict__ qb, const ushort* __restrict__ kb,
            const ushort* __restrict__ vt, ushort* __restrict__ ao)
{
    __shared__ ushort Ks[2][64 * 64];
    __shared__ ushort Vs[2][64 * 64];   // V^T tile: row = d, col = k_local (swizzled)

    // XCD-aware remap: 1024 blocks -> XCD (lid&7) gets contiguous chunk of 128.
    const int lid = blockIdx.x + blockIdx.y * 16;
    const int nl  = ((lid & 7) << 7) | (lid >> 3);
    const int bh    = nl >> 4;        // 0..63
    const int qpair = nl & 15;        // 0..15
    const int t = threadIdx.x;
    const int lane = t & 63, wv = t >> 6;
    const int l15 = lane & 15, quad = lane >> 4;
    const int b = bh >> 4, h = bh & 15;

    const ushort* kB = kb + (size_t)bh * SEQ * HDIM;
    const ushort* vB = vt + (size_t)bh * HDIM * SEQ;

    const int rowA = wv * 16 + (lane >> 3);
    const int cg   = (lane & 7) ^ ((lane >> 3) & 7);
    const int koffA = rowA * HDIM + cg * 8;
    const int voffA = rowA * SEQ + cg * 8;

    const int x7 = l15 & 7;
    const int rd0 = l15 * 64 + ((quad ^ x7) * 8);
    const int rd1 = l15 * 64 + (((quad + 4) ^ x7) * 8);

    const int qlo = (quad & 1) * 2;
    const bool hi = (quad >= 2);

#define STAGE(bufi, kt_) do {                                          \
        const int k0_ = (kt_) * 64;                                    \
        ushort* ldsK_ = &Ks[(bufi)][wv * 16 * 64];                     \
        ushort* ldsV_ = &Vs[(bufi)][wv * 16 * 64];                     \
        gl_lds16(kB + (size_t)k0_ * HDIM + koffA,            ldsK_);          \
        gl_lds16(kB + (size_t)k0_ * HDIM + koffA + 8 * HDIM, ldsK_ + 8 * 64); \
        gl_lds16(vB + (size_t)k0_ + voffA,                   ldsV_);          \
        gl_lds16(vB + (size_t)k0_ + voffA + 8 * SEQ,         ldsV_ + 8 * 64); \
    } while (0)

#pragma unroll 1
    for (int p = 0; p < 2; p++) {
        const int qt = p ? (31 - qpair) : qpair;
        const int q0 = qt * 64;
        const int qg = q0 + wv * 16 + l15;

        const ushort* qaL = qb + ((size_t)bh * SEQ + qg) * HDIM + quad * 8;
        bf16x8 qa[2];
        qa[0] = *(const bf16x8*)(qaL);
        qa[1] = *(const bf16x8*)(qaL + 32);

        f32x4 accO[4];
#pragma unroll
        for (int i = 0; i < 4; i++) accO[i] = (f32x4){0.f, 0.f, 0.f, 0.f};
        float m = -30000.f, l = 0.f;

        // Pass boundary: all waves done reading prior pass's LDS before the
        // prologue DMA overwrites buf 0.
        __syncthreads();
        STAGE(0, 0);

#pragma unroll 1
        for (int kt = 0; kt <= qt; kt++) {
            const int buf = kt & 1;
            const ushort* KsB = Ks[buf];
            const ushort* VsB = Vs[buf];
            __syncthreads();               // drains DMA for buf (vmcnt at barrier)
            if (kt < qt) STAGE(buf ^ 1, kt + 1);   // overlap next tile with compute

            f32x4 st[4];
#pragma unroll
            for (int mi = 0; mi < 4; mi++) st[mi] = (f32x4){0.f, 0.f, 0.f, 0.f};
            __builtin_amdgcn_s_setprio(1);
#pragma unroll
            for (int mi = 0; mi < 4; mi++) {
                bf16x8 ka0 = *(const bf16x8*)&KsB[mi * 1024 + rd0];
                st[mi] = __builtin_amdgcn_mfma_f32_16x16x32_bf16(ka0, qa[0], st[mi], 0, 0, 0);
            }
#pragma unroll
            for (int mi = 0; mi < 4; mi++) {
                bf16x8 ka1 = *(const bf16x8*)&KsB[mi * 1024 + rd1];
                st[mi] = __builtin_amdgcn_mfma_f32_16x16x32_bf16(ka1, qa[1], st[mi], 0, 0, 0);
            }
            __builtin_amdgcn_s_setprio(0);

            if (kt == qt) {
#pragma unroll
                for (int mi = 0; mi < 4; mi++)
#pragma unroll
                    for (int r = 0; r < 4; r++) {
                        int kg = kt * 64 + mi * 16 + quad * 4 + r;
                        if (kg > qg) st[mi][r] = -30000.f;
                    }
            }

            float a0 = fmaxf(fmaxf(st[0][0], st[0][1]), fmaxf(st[0][2], st[0][3]));
            float a1 = fmaxf(fmaxf(st[1][0], st[1][1]), fmaxf(st[1][2], st[1][3]));
            float a2 = fmaxf(fmaxf(st[2][0], st[2][1]), fmaxf(st[2][2], st[2][3]));
            float a3 = fmaxf(fmaxf(st[3][0], st[3][1]), fmaxf(st[3][2], st[3][3]));
            float mx = fmaxf(fmaxf(a0, a1), fmaxf(a2, a3));
            mx = fmaxf(mx, __shfl_xor(mx, 16));
            mx = fmaxf(mx, __shfl_xor(mx, 32));

            // T13 defer-max: only rescale when the running max grew by >8.
            if (!__all(mx - m <= 8.0f)) {
                const float mnew = fmaxf(m, mx);
                const float alpha = __expf(m - mnew);
#pragma unroll
                for (int mi = 0; mi < 4; mi++)
#pragma unroll
                    for (int r = 0; r < 4; r++) accO[mi][r] *= alpha;
                l *= alpha;
                m = mnew;
            }

            float s0 = 0.f, s1 = 0.f, s2 = 0.f, s3 = 0.f;
#pragma unroll
            for (int mi = 0; mi < 4; mi++) {
                float p0 = __expf(st[mi][0] - m);
                float p1 = __expf(st[mi][1] - m);
                float p2 = __expf(st[mi][2] - m);
                float p3 = __expf(st[mi][3] - m);
                st[mi][0] = p0; st[mi][1] = p1; st[mi][2] = p2; st[mi][3] = p3;
                s0 += p0; s1 += p1; s2 += p2; s3 += p3;
            }
            float ssum = (s0 + s1) + (s2 + s3);
            ssum += __shfl_xor(ssum, 16);
            ssum += __shfl_xor(ssum, 32);
            l += ssum;

            uint32_t pr[4][2];
#pragma unroll
            for (int mi = 0; mi < 4; mi++) {
                pr[mi][0] = pk2(st[mi][0], st[mi][1]);
                pr[mi][1] = pk2(st[mi][2], st[mi][3]);
            }

#pragma unroll
            for (int ks2 = 0; ks2 < 2; ks2++) {
                uint32_t pb[4];
#pragma unroll
                for (int w = 0; w < 4; w++) {
                    int srcLane = (qlo + (w >> 1)) * 16 + l15;
                    uint32_t va = __shfl(pr[ks2 * 2 + 0][w & 1], srcLane);
                    uint32_t vb = __shfl(pr[ks2 * 2 + 1][w & 1], srcLane);
                    pb[w] = hi ? vb : va;
                }
                bf16x8 pfrag;
                *(uint4*)&pfrag = *(uint4*)pb;
                const int rdv = ks2 ? rd1 : rd0;
                __builtin_amdgcn_s_setprio(1);
#pragma unroll
                for (int mi = 0; mi < 4; mi++) {
                    bf16x8 vfr = *(const bf16x8*)&VsB[mi * 1024 + rdv];
                    accO[mi] = __builtin_amdgcn_mfma_f32_16x16x32_bf16(vfr, pfrag, accO[mi], 0, 0, 0);
                }
                __builtin_amdgcn_s_setprio(0);
            }
        }

        const float rl = 1.0f / fmaxf(l, 1e-20f);
#pragma unroll
        for (int mi = 0; mi < 4; mi++) {
            uint2 o;
            o.x = pk2(accO[mi][0] * rl, accO[mi][1] * rl);
            o.y = pk2(accO[mi][2] * rl, accO[mi][3] * rl);
            *(uint2*)&ao[((size_t)(b * SEQ + qg)) * D_MODEL + h * HDIM + mi * 16 + quad * 4] = o;
        }
    }
#undef STAGE
}

// ---------------------------------------------------------------------------
extern "C" void kernel_launch(void* const* d_in, const int* in_sizes, int n_in,
                              void* d_out, int out_size, void* d_ws, size_t ws_size,
                              hipStream_t stream)
{
    (void)out_size; (void)ws_size;
    int ix = 0, iwq = 1, iwo = 2;
    for (int i = 0; i < n_in; i++) {
        if (in_sizes[i] == 4 * SEQ * D_MODEL)          ix  = i;  // 8388608
        else if (in_sizes[i] == 3 * D_MODEL * D_MODEL) iwq = i;  // 3145728
        else if (in_sizes[i] == D_MODEL * D_MODEL)     iwo = i;  // 1048576
    }
    const float* X    = (const float*)d_in[ix];
    const float* Wqkv = (const float*)d_in[iwq];
    const float* Wout = (const float*)d_in[iwo];
    float* out = (float*)d_out;

    char* ws = (char*)d_ws;
    const size_t SZ = (size_t)BH * SEQ * HDIM * sizeof(ushort);  // 16.78 MB
    ushort* xb = (ushort*)(ws);            // X in bf16; reused as ao after gemm_qkv
    ushort* qb = (ushort*)(ws + SZ);
    ushort* kb = (ushort*)(ws + 2 * SZ);
    ushort* vt = (ushort*)(ws + 3 * SZ);
    ushort* wqb = (ushort*)(ws + 4 * SZ);                        // 6.29 MB
    ushort* wob = (ushort*)(ws + 4 * SZ + 3 * (size_t)D_MODEL * D_MODEL * 2);
    ushort* ao = xb;                       // alias: xb dead after gemm_qkv

    cvt_k<<<dim3(6144), 256, 0, stream>>>(X, xb, Wqkv, wqb, Wout, wob);
    gemm_qkv<<<dim3(24, 64), 256, 0, stream>>>(xb, wqb, qb, kb, vt);
    attn_k<<<dim3(16, 64), 256, 0, stream>>>(qb, kb, vt, ao);
    gemm_out<<<dim3(8, 64), 256, 0, stream>>>(ao, wob, out);
}